// Round 12
// baseline (680.947 us; speedup 1.0000x reference)
//
#include <hip/hip_runtime.h>
#include <hip/hip_bf16.h>
#include <hip/hip_cooperative_groups.h>
#include <cstdint>

namespace cg = cooperative_groups;

#define NEG 0.2f
#define SBS 256        // scan tile size (nodes per tile)
#define PADK 56        // LDS col stride (ushorts): 112B, 16B-aligned, conflict-free
#define COOP_BLOCKS 1024

typedef __attribute__((ext_vector_type(8))) short bf16x8;
typedef __attribute__((ext_vector_type(8))) unsigned short ushort8;
typedef __attribute__((ext_vector_type(4))) float f32x4;

__device__ __forceinline__ float bf2f(unsigned short u){
  return __uint_as_float(((unsigned)u)<<16);
}
__device__ __forceinline__ unsigned short f2bf(float f){
  __hip_bfloat16 b = __float2bfloat16(f);   // RNE
  return *reinterpret_cast<unsigned short*>(&b);
}

// ---- embed (+Bt2 on extra blocks): w_att in LDS, thread-per-node ----
__global__ __launch_bounds__(256)
void embed_kernel(const float* __restrict__ x, const float* __restrict__ emb_w,
                  const float* __restrict__ emb_b, const float* __restrict__ gat_w,
                  const float* __restrict__ att_src, const float* __restrict__ att_dst,
                  unsigned short* __restrict__ h_bf, float* __restrict__ a_s,
                  float* __restrict__ a_d, unsigned short* __restrict__ Bt2,
                  int nN, int nB)
{
  int tid = threadIdx.x;
  if ((int)blockIdx.x >= nB){
    // Bt2 builder blocks: Bt2[ks][col][kk] = gat_w^T / 3
    int i = (blockIdx.x - nB)*256 + tid;   // 0..49151
    if (i < 12*128*32){
      int ks  = i >> 12;
      int rem = i & 4095;
      int col = rem >> 5;
      int kk  = rem & 31;
      int t = ks*32 + kk;            // h*128 + k
      int h = t >> 7, k = t & 127;
      Bt2[i] = f2bf(gat_w[(size_t)k*384 + h*128 + col] * (1.f/3.f));
    }
    return;
  }

  __shared__ float watt[768];     // [0:384)=src (h*128+k), [384:768)=dst
  #pragma unroll
  for (int r=0;r<3;r++){
    int o = tid + r*256;          // 0..767
    int isD = (o >= 384);
    int t2 = isD ? (o-384) : o;
    int h = t2 >> 7, k = t2 & 127;
    const float* att = isD ? (att_dst + h*128) : (att_src + h*128);
    const float* gw  = gat_w + (size_t)k*384 + h*128;
    float dot = 0.f;
    #pragma unroll 8
    for (int c=0;c<128;c++) dot += gw[c]*att[c];
    watt[o] = dot;
  }
  __syncthreads();

  int n = blockIdx.x*256 + tid;
  if (n >= nN) return;

  float xv[9];
  #pragma unroll
  for (int k=0;k<9;k++) xv[k] = x[(size_t)n*9 + k];

  float s0=0.f,s1=0.f,s2=0.f, d0=0.f,d1=0.f,d2=0.f;
  unsigned short* hrow = h_bf + (size_t)n*128;

  #pragma unroll 4
  for (int c0=0; c0<128; c0+=8){
    unsigned short pk[8];
    #pragma unroll
    for (int j=0;j<8;j++){
      int c = c0 + j;
      float acc = emb_b[c];
      #pragma unroll
      for (int k=0;k<9;k++) acc += xv[k]*emb_w[k*128+c];
      pk[j] = f2bf(acc);
      s0 += acc*watt[c]; s1 += acc*watt[128+c]; s2 += acc*watt[256+c];
      d0 += acc*watt[384+c]; d1 += acc*watt[512+c]; d2 += acc*watt[640+c];
    }
    *(int4*)(hrow + c0) = *(int4*)pk;
  }
  a_s[(size_t)n*3+0]=s0; a_s[(size_t)n*3+1]=s1; a_s[(size_t)n*3+2]=s2;
  a_d[(size_t)n*3+0]=d0; a_d[(size_t)n*3+1]=d1; a_d[(size_t)n*3+2]=d2;
}

// ---- cooperative CSR build: zero -> histogram -> blocksum -> scan -> scatter ----
__global__ __launch_bounds__(256)
void csr_coop(const int* __restrict__ ei, int* __restrict__ deg,
              int* __restrict__ bsum, int* __restrict__ boff,
              int* __restrict__ rowptr, int* __restrict__ cursor,
              int* __restrict__ csr, int nN, int nE, int nB)
{
  cg::grid_group grid = cg::this_grid();
  int tid  = threadIdx.x;
  int gtid = blockIdx.x*256 + tid;
  int gsz  = gridDim.x*256;

  // phase a: zero deg
  for (int i=gtid; i<nN; i+=gsz) deg[i] = 0;
  grid.sync();

  // phase b: histogram of dst (scattered atomics over 50K counters)
  for (int e=gtid; e<nE; e+=gsz) atomicAdd(&deg[ei[nE + e]], 1);
  grid.sync();

  // phase c: per-tile sums (tile = blockIdx if < nB)
  if ((int)blockIdx.x < nB){
    int i = blockIdx.x*SBS + tid;
    int v = (i < nN) ? deg[i] : 0;
    #pragma unroll
    for (int off=32; off; off>>=1) v += __shfl_down(v, off);
    __shared__ int ws[SBS/64];
    if ((tid&63)==0) ws[tid>>6] = v;
    __syncthreads();
    if (tid==0){
      int s=0;
      #pragma unroll
      for (int i2=0;i2<SBS/64;i2++) s += ws[i2];
      bsum[blockIdx.x]=s;
    }
  }
  grid.sync();

  // phase d: scan of tile sums (block 0)
  if (blockIdx.x == 0){
    __shared__ int s[256];
    int v = (tid < nB) ? bsum[tid] : 0;
    s[tid] = v;
    __syncthreads();
    for (int off=1; off<256; off<<=1){
      int add = (tid >= off) ? s[tid-off] : 0;
      __syncthreads();
      s[tid] += add;
      __syncthreads();
    }
    if (tid < nB) boff[tid] = (tid==0) ? 0 : s[tid-1];
  }
  grid.sync();

  // phase e: per-tile exclusive scan -> rowptr / cursor
  if ((int)blockIdx.x < nB){
    __shared__ int s[SBS];
    int i = blockIdx.x*SBS + tid;
    int v = (i < nN) ? deg[i] : 0;
    s[tid] = v;
    __syncthreads();
    for (int off=1; off<SBS; off<<=1){
      int add = (tid >= off) ? s[tid-off] : 0;
      __syncthreads();
      s[tid] += add;
      __syncthreads();
    }
    int excl = boff[blockIdx.x] + ((tid==0) ? 0 : s[tid-1]);
    if (i < nN){ rowptr[i] = excl; cursor[i] = excl; }
    if (i == nN-1) rowptr[nN] = excl + v;
  }
  grid.sync();

  // phase f: scatter src ids into CSR rows
  for (int e=gtid; e<nE; e+=gsz){
    int s = ei[e], d = ei[nE + e];
    int pos = atomicAdd(&cursor[d], 1);
    csr[pos] = s;
  }
}

// ---- gather v4: 8 nodes per wave (8-lane groups), 16 ch/lane, 2x unroll ----
__global__ __launch_bounds__(256)
void gather_kernel(const int* __restrict__ rowptr, const int* __restrict__ csr,
                   const float* __restrict__ a_s, const float* __restrict__ a_d,
                   const unsigned short* __restrict__ h_bf,
                   unsigned short* __restrict__ hagg, int nN)
{
  int wave = threadIdx.x >> 6, lane = threadIdx.x & 63;
  int g   = lane >> 3;          // group within wave (0..7)
  int lin = lane & 7;           // lane within group
  int gb  = lane & 56;          // group base lane
  int n = blockIdx.x*32 + wave*8 + g;
  int valid = (n < nN);
  int nc = valid ? n : (nN-1);

  int ro  = rowptr[nc];
  int deg = rowptr[nc+1] - ro;
  int degT = valid ? (deg + 1) : 0;       // + self loop

  float ad0 = a_d[(size_t)nc*3+0], ad1 = a_d[(size_t)nc*3+1], ad2 = a_d[(size_t)nc*3+2];

  float a0[16], a1[16], a2[16];
  #pragma unroll
  for (int c=0;c<16;c++){ a0[c]=0.f; a1[c]=0.f; a2[c]=0.f; }
  float d0=0.f, d1=0.f, d2=0.f;

  const unsigned short* hb = h_bf + 16*lin;

  for (int base=0; base<degT; base+=8){
    int i = base + lin;
    int sReg = nc; float p0=0.f, p1=0.f, p2=0.f;
    if (i < degT){
      int s = (i < deg) ? csr[ro+i] : nc;
      sReg = s;
      float e0 = a_s[(size_t)s*3+0] + ad0; e0 = e0>0.f ? e0 : NEG*e0;
      float e1 = a_s[(size_t)s*3+1] + ad1; e1 = e1>0.f ? e1 : NEG*e1;
      float e2 = a_s[(size_t)s*3+2] + ad2; e2 = e2>0.f ? e2 : NEG*e2;
      p0 = __expf(e0); p1 = __expf(e1); p2 = __expf(e2);
      d0 += p0; d1 += p1; d2 += p2;
    }
    int cnt = min(8, degT - base);
    int j = 0;
    for (; j+1 < cnt; j += 2){
      int   sA = __shfl(sReg, gb+j);
      int   sB = __shfl(sReg, gb+j+1);
      float A0 = __shfl(p0, gb+j),   A1 = __shfl(p1, gb+j),   A2 = __shfl(p2, gb+j);
      float B0 = __shfl(p0, gb+j+1), B1 = __shfl(p1, gb+j+1), B2 = __shfl(p2, gb+j+1);
      const unsigned short* ra = hb + (size_t)sA*128;
      const unsigned short* rb = hb + (size_t)sB*128;
      ushort8 ha0 = *(const ushort8*)(ra), ha1 = *(const ushort8*)(ra+8);
      ushort8 hb0 = *(const ushort8*)(rb), hb1 = *(const ushort8*)(rb+8);
      #pragma unroll
      for (int c=0;c<8;c++){
        float fa = bf2f(ha0[c]), fb = bf2f(hb0[c]);
        a0[c] += A0*fa + B0*fb;
        a1[c] += A1*fa + B1*fb;
        a2[c] += A2*fa + B2*fb;
      }
      #pragma unroll
      for (int c=0;c<8;c++){
        float fa = bf2f(ha1[c]), fb = bf2f(hb1[c]);
        a0[8+c] += A0*fa + B0*fb;
        a1[8+c] += A1*fa + B1*fb;
        a2[8+c] += A2*fa + B2*fb;
      }
    }
    if (j < cnt){
      int   sA = __shfl(sReg, gb+j);
      float A0 = __shfl(p0, gb+j), A1 = __shfl(p1, gb+j), A2 = __shfl(p2, gb+j);
      const unsigned short* ra = hb + (size_t)sA*128;
      ushort8 ha0 = *(const ushort8*)(ra), ha1 = *(const ushort8*)(ra+8);
      #pragma unroll
      for (int c=0;c<8;c++){
        float fa = bf2f(ha0[c]);
        a0[c] += A0*fa; a1[c] += A1*fa; a2[c] += A2*fa;
      }
      #pragma unroll
      for (int c=0;c<8;c++){
        float fa = bf2f(ha1[c]);
        a0[8+c] += A0*fa; a1[8+c] += A1*fa; a2[8+c] += A2*fa;
      }
    }
  }

  // denom reduction within 8-lane group
  #pragma unroll
  for (int off=1; off<8; off<<=1){
    d0 += __shfl_xor(d0, off);
    d1 += __shfl_xor(d1, off);
    d2 += __shfl_xor(d2, off);
  }

  if (valid){
    float w0 = 1.f/(d0+1e-16f);
    float w1 = 1.f/(d1+1e-16f);
    float w2 = 1.f/(d2+1e-16f);
    unsigned short o0[16], o1[16], o2[16];
    #pragma unroll
    for (int c=0;c<16;c++){
      o0[c] = f2bf(a0[c]*w0);
      o1[c] = f2bf(a1[c]*w1);
      o2[c] = f2bf(a2[c]*w2);
    }
    size_t bi = (size_t)n*384 + 16*lin;
    *(int4*)(hagg + bi      ) = *(int4*)(o0);
    *(int4*)(hagg + bi +   8) = *(int4*)(o0+8);
    *(int4*)(hagg + bi + 128) = *(int4*)(o1);
    *(int4*)(hagg + bi + 136) = *(int4*)(o1+8);
    *(int4*)(hagg + bi + 256) = *(int4*)(o2);
    *(int4*)(hagg + bi + 264) = *(int4*)(o2+8);
  }
}

// ---- gemm2: LDS-staged B, double-buffered, software-pipelined ----
__global__ __launch_bounds__(256)
void gemm2_kernel(const unsigned short* __restrict__ hagg,
                  const unsigned short* __restrict__ Bt2,
                  const unsigned short* __restrict__ h_bf,
                  const float* __restrict__ gat_bias,
                  const float* __restrict__ out_w, const float* __restrict__ out_b,
                  float* __restrict__ out, int nN)
{
  __shared__ __align__(16) unsigned short Bs[2][128*PADK];
  int tid  = threadIdx.x;
  int wave = tid >> 6, lane = tid & 63;
  int cl = lane & 15, kg = lane >> 4;
  int r0 = blockIdx.x*64 + wave*16;
  int rowA = min(r0 + cl, nN-1);
  const unsigned short* aBase = hagg + (size_t)rowA*384 + kg*8;

  int scol = tid >> 1, shalf = tid & 1;
  int dstI = scol*(PADK/8) + shalf*2;

  {
    const int4* src = (const int4*)Bt2;
    int4 t0 = src[2*tid], t1 = src[2*tid+1];
    ((int4*)Bs[0])[dstI]   = t0;
    ((int4*)Bs[0])[dstI+1] = t1;
  }
  f32x4 acc[8];
  #pragma unroll
  for (int f=0;f<8;f++) acc[f] = (f32x4){0.f,0.f,0.f,0.f};
  bf16x8 aCur = *(const bf16x8*)(aBase);
  __syncthreads();

  #pragma unroll
  for (int ks=0; ks<12; ks++){
    int4 t0, t1; bf16x8 aNext;
    if (ks < 11){
      const int4* src = (const int4*)(Bt2 + (size_t)(ks+1)*4096);
      t0 = src[2*tid]; t1 = src[2*tid+1];
      aNext = *(const bf16x8*)(aBase + (ks+1)*32);
    }
    const unsigned short* bs = Bs[ks & 1];
    #pragma unroll
    for (int f=0;f<8;f++){
      bf16x8 b = *(const bf16x8*)(bs + (f*16 + cl)*PADK + kg*8);
      acc[f] = __builtin_amdgcn_mfma_f32_16x16x32_bf16(aCur, b, acc[f], 0, 0, 0);
    }
    if (ks < 11){
      int4* dst = (int4*)Bs[(ks+1) & 1];
      dst[dstI]   = t0;
      dst[dstI+1] = t1;
      aCur = aNext;
    }
    __syncthreads();
  }

  float p[4][4];
  #pragma unroll
  for (int r=0;r<4;r++)
    #pragma unroll
    for (int j=0;j<4;j++) p[r][j]=0.f;

  #pragma unroll
  for (int f=0;f<8;f++){
    int col = f*16 + cl;
    float bias = gat_bias[col];
    float w0=out_w[col*4+0], w1=out_w[col*4+1], w2=out_w[col*4+2], w3=out_w[col*4+3];
    #pragma unroll
    for (int r=0;r<4;r++){
      int row = r0 + kg*4 + r;
      float hres = (row < nN) ? bf2f(h_bf[(size_t)row*128 + col]) : 0.f;
      float xn = acc[f][r] + bias + hres;
      p[r][0] += xn*w0; p[r][1] += xn*w1; p[r][2] += xn*w2; p[r][3] += xn*w3;
    }
  }
  #pragma unroll
  for (int off=1; off<16; off<<=1){
    #pragma unroll
    for (int r=0;r<4;r++)
      #pragma unroll
      for (int j=0;j<4;j++) p[r][j] += __shfl_xor(p[r][j], off);
  }
  if (cl == 0){
    #pragma unroll
    for (int r=0;r<4;r++){
      int row = r0 + kg*4 + r;
      if (row < nN){
        float4 o = {p[r][0]+out_b[0], p[r][1]+out_b[1], p[r][2]+out_b[2], p[r][3]+out_b[3]};
        *(float4*)(out + (size_t)row*4) = o;
      }
    }
  }
}

extern "C" void kernel_launch(void* const* d_in, const int* in_sizes, int n_in,
                              void* d_out, int out_size, void* d_ws, size_t ws_size,
                              hipStream_t stream) {
  const float* x       = (const float*)d_in[0];
  const float* emb_w   = (const float*)d_in[1];
  const float* emb_b   = (const float*)d_in[2];
  const float* gat_w   = (const float*)d_in[3];
  const float* att_src = (const float*)d_in[4];
  const float* att_dst = (const float*)d_in[5];
  const float* gat_bias= (const float*)d_in[6];
  const float* out_w   = (const float*)d_in[7];
  const float* out_b   = (const float*)d_in[8];
  const int*   ei      = (const int*)d_in[9];
  float* out = (float*)d_out;

  int nN = in_sizes[0]/9;
  int nE = in_sizes[9]/2;
  int nB = (nN + SBS - 1) / SBS;     // 196

  char* p = (char*)d_ws;
  auto alloc = [&](size_t bytes)->char*{
    char* r = p; p += (bytes + 255) & ~(size_t)255; return r;
  };
  unsigned short* h_bf   = (unsigned short*)alloc((size_t)nN*128*2);
  float*          a_s    = (float*)         alloc((size_t)nN*3*4);
  float*          a_d    = (float*)         alloc((size_t)nN*3*4);
  unsigned short* Bt2    = (unsigned short*)alloc((size_t)12*128*32*2);
  int*            deg    = (int*)           alloc((size_t)nN*4);
  int*            rowptr = (int*)           alloc(((size_t)nN+1)*4);
  int*            cursor = (int*)           alloc((size_t)nN*4);
  int*            csr    = (int*)           alloc((size_t)nE*4);
  int*            bsum   = (int*)           alloc((size_t)nB*4);
  int*            boff   = (int*)           alloc((size_t)nB*4);
  unsigned short* hagg   = (unsigned short*)alloc((size_t)nN*384*2);

  // dispatch 1: embed (+ Bt2 builder blocks)
  embed_kernel<<<nB + 192, 256, 0, stream>>>(
      x, emb_w, emb_b, gat_w, att_src, att_dst, h_bf, a_s, a_d, Bt2, nN, nB);

  // dispatch 2: cooperative CSR build (zero->hist->blocksum->scan->blockscan->scatter)
  {
    const int* ei_   = ei;
    int* deg_    = deg;
    int* bsum_   = bsum;
    int* boff_   = boff;
    int* rowptr_ = rowptr;
    int* cursor_ = cursor;
    int* csr_    = csr;
    int nN_ = nN, nE_ = nE, nB_ = nB;
    void* args[] = { (void*)&ei_, (void*)&deg_, (void*)&bsum_, (void*)&boff_,
                     (void*)&rowptr_, (void*)&cursor_, (void*)&csr_,
                     (void*)&nN_, (void*)&nE_, (void*)&nB_ };
    hipLaunchCooperativeKernel((const void*)csr_coop, dim3(COOP_BLOCKS), dim3(256),
                               args, 0, stream);
  }

  // dispatch 3: gather
  gather_kernel<<<(nN+31)/32, 256, 0, stream>>>(
      rowptr, csr, a_s, a_d, h_bf, hagg, nN);

  // dispatch 4: gemm2
  gemm2_kernel<<<(nN+63)/64, 256, 0, stream>>>(
      hagg, Bt2, h_bf, gat_bias, out_w, out_b, out, nN);
}

// Round 13
// 208.046 us; speedup vs baseline: 3.2731x; 3.2731x over previous
//
#include <hip/hip_runtime.h>
#include <hip/hip_bf16.h>
#include <cstdint>

#define NEG 0.2f
#define SBS 256        // scan tile size (nodes per tile)
#define PADK 56        // LDS col stride (ushorts): 112B, 16B-aligned, conflict-free

typedef __attribute__((ext_vector_type(8))) short bf16x8;
typedef __attribute__((ext_vector_type(8))) unsigned short ushort8;
typedef __attribute__((ext_vector_type(4))) float f32x4;

__device__ __forceinline__ float bf2f(unsigned short u){
  return __uint_as_float(((unsigned)u)<<16);
}
__device__ __forceinline__ unsigned short f2bf(float f){
  __hip_bfloat16 b = __float2bfloat16(f);   // RNE
  return *reinterpret_cast<unsigned short*>(&b);
}

// ---- embed: per-block w_att in LDS, thread-per-node h/a_s/a_d; zeroes deg ----
__global__ __launch_bounds__(256)
void embed_kernel(const float* __restrict__ x, const float* __restrict__ emb_w,
                  const float* __restrict__ emb_b, const float* __restrict__ gat_w,
                  const float* __restrict__ att_src, const float* __restrict__ att_dst,
                  unsigned short* __restrict__ h_bf, float* __restrict__ a_s,
                  float* __restrict__ a_d, int* __restrict__ deg, int nN)
{
  __shared__ float watt[768];     // [0:384)=src (h*128+k), [384:768)=dst
  int tid = threadIdx.x;

  #pragma unroll
  for (int r=0;r<3;r++){
    int o = tid + r*256;          // 0..767
    int isD = (o >= 384);
    int t2 = isD ? (o-384) : o;
    int h = t2 >> 7, k = t2 & 127;
    const float* att = isD ? (att_dst + h*128) : (att_src + h*128);
    const float* gw  = gat_w + (size_t)k*384 + h*128;
    float dot = 0.f;
    #pragma unroll 8
    for (int c=0;c<128;c++) dot += gw[c]*att[c];
    watt[o] = dot;
  }
  __syncthreads();

  int n = blockIdx.x*256 + tid;
  if (n < nN) deg[n] = 0;         // zeroed for the histogram that follows
  if (n >= nN) return;

  float xv[9];
  #pragma unroll
  for (int k=0;k<9;k++) xv[k] = x[(size_t)n*9 + k];

  float s0=0.f,s1=0.f,s2=0.f, d0=0.f,d1=0.f,d2=0.f;
  unsigned short* hrow = h_bf + (size_t)n*128;

  #pragma unroll 4
  for (int c0=0; c0<128; c0+=8){
    unsigned short pk[8];
    #pragma unroll
    for (int j=0;j<8;j++){
      int c = c0 + j;
      float acc = emb_b[c];
      #pragma unroll
      for (int k=0;k<9;k++) acc += xv[k]*emb_w[k*128+c];
      pk[j] = f2bf(acc);
      s0 += acc*watt[c]; s1 += acc*watt[128+c]; s2 += acc*watt[256+c];
      d0 += acc*watt[384+c]; d1 += acc*watt[512+c]; d2 += acc*watt[640+c];
    }
    *(int4*)(hrow + c0) = *(int4*)pk;
  }
  a_s[(size_t)n*3+0]=s0; a_s[(size_t)n*3+1]=s1; a_s[(size_t)n*3+2]=s2;
  a_d[(size_t)n*3+0]=d0; a_d[(size_t)n*3+1]=d1; a_d[(size_t)n*3+2]=d2;
}

// ---- deg histogram (scattered atomics); extra blocks build Bt2 ----
__global__ __launch_bounds__(256)
void deg_kernel(const int* __restrict__ ei, int* __restrict__ deg,
                const float* __restrict__ gat_w,
                unsigned short* __restrict__ Bt2, int nE, int ebN)
{
  if (blockIdx.x < (unsigned)ebN){
    int e = blockIdx.x*256 + threadIdx.x;
    if (e < nE) atomicAdd(&deg[ei[nE + e]], 1);
  } else {
    int i = (blockIdx.x - ebN)*256 + threadIdx.x;   // 0..49151
    if (i < 12*128*32){
      int ks  = i >> 12;
      int rem = i & 4095;
      int col = rem >> 5;
      int kk  = rem & 31;
      int t = ks*32 + kk;            // h*128 + k
      int h = t >> 7, k = t & 127;
      Bt2[i] = f2bf(gat_w[(size_t)k*384 + h*128 + col] * (1.f/3.f));
    }
  }
}

// ---- blocksum over deg+1 (self-loop slot reserved per node) ----
__global__ __launch_bounds__(SBS)
void blocksum_kernel(const int* __restrict__ deg, int* __restrict__ bsum, int nN)
{
  int i = blockIdx.x*SBS + threadIdx.x;
  int v = (i < nN) ? deg[i]+1 : 0;
  #pragma unroll
  for (int off=32; off; off>>=1) v += __shfl_down(v, off);
  __shared__ int ws[SBS/64];
  if ((threadIdx.x&63)==0) ws[threadIdx.x>>6] = v;
  __syncthreads();
  if (threadIdx.x==0){
    int s=0;
    #pragma unroll
    for (int i2=0;i2<SBS/64;i2++) s += ws[i2];
    bsum[blockIdx.x]=s;
  }
}

// ---- scan of tile sums (nB <= 256) ----
__global__ __launch_bounds__(256)
void scansum_kernel(const int* __restrict__ bsum, int* __restrict__ boff, int nB)
{
  __shared__ int s[256];
  int t = threadIdx.x;
  int v = (t < nB) ? bsum[t] : 0;
  s[t] = v;
  __syncthreads();
  for (int off=1; off<256; off<<=1){
    int add = (t >= off) ? s[t-off] : 0;
    __syncthreads();
    s[t] += add;
    __syncthreads();
  }
  if (t < nB) boff[t] = (t==0) ? 0 : s[t-1];
}

__global__ __launch_bounds__(SBS)
void blockscan_kernel(const int* __restrict__ deg, const int* __restrict__ boff,
                      int* __restrict__ rowptr, int* __restrict__ cursor, int nN)
{
  __shared__ int s[SBS];
  int t = threadIdx.x;
  int i = blockIdx.x*SBS + t;
  int v = (i < nN) ? deg[i]+1 : 0;
  s[t] = v;
  __syncthreads();
  for (int off=1; off<SBS; off<<=1){
    int add = (t >= off) ? s[t-off] : 0;
    __syncthreads();
    s[t] += add;
    __syncthreads();
  }
  int excl = boff[blockIdx.x] + ((t==0) ? 0 : s[t-1]);
  if (i < nN){ rowptr[i] = excl; cursor[i] = excl; }
  if (i == nN-1) rowptr[nN] = excl + v;
}

// ---- scatter v2: per-edge alpha precompute -> val4 {p0,p1,p2,src};
//      extra blocks fill each node's self-loop slot (last of its row) ----
__global__ __launch_bounds__(256)
void scatter_kernel(const int* __restrict__ ei, int* __restrict__ cursor,
                    const float* __restrict__ a_s, const float* __restrict__ a_d,
                    const int* __restrict__ rowptr, float4* __restrict__ val,
                    int nE, int ebN, int nN)
{
  if (blockIdx.x < (unsigned)ebN){
    int e = blockIdx.x*256 + threadIdx.x;
    if (e < nE){
      int s = ei[e], d = ei[nE + e];
      float e0 = a_s[(size_t)s*3+0] + a_d[(size_t)d*3+0]; e0 = e0>0.f ? e0 : NEG*e0;
      float e1 = a_s[(size_t)s*3+1] + a_d[(size_t)d*3+1]; e1 = e1>0.f ? e1 : NEG*e1;
      float e2 = a_s[(size_t)s*3+2] + a_d[(size_t)d*3+2]; e2 = e2>0.f ? e2 : NEG*e2;
      int pos = atomicAdd(&cursor[d], 1);
      val[pos] = make_float4(__expf(e0), __expf(e1), __expf(e2), __int_as_float(s));
    }
  } else {
    int n = (blockIdx.x - ebN)*256 + threadIdx.x;
    if (n < nN){
      float e0 = a_s[(size_t)n*3+0] + a_d[(size_t)n*3+0]; e0 = e0>0.f ? e0 : NEG*e0;
      float e1 = a_s[(size_t)n*3+1] + a_d[(size_t)n*3+1]; e1 = e1>0.f ? e1 : NEG*e1;
      float e2 = a_s[(size_t)n*3+2] + a_d[(size_t)n*3+2]; e2 = e2>0.f ? e2 : NEG*e2;
      val[rowptr[n+1]-1] = make_float4(__expf(e0), __expf(e1), __expf(e2),
                                       __int_as_float(n));
    }
  }
}

// ---- gather v5: 4 nodes/wave (16-lane groups), shuffle-free, exp-free ----
__global__ __launch_bounds__(256)
void gather_kernel(const int* __restrict__ rowptr, const float4* __restrict__ val,
                   const unsigned short* __restrict__ h_bf,
                   unsigned short* __restrict__ hagg, int nN)
{
  int wave = threadIdx.x >> 6, lane = threadIdx.x & 63;
  int g   = lane >> 4;          // group within wave (0..3)
  int lin = lane & 15;          // lane within group -> 8 channels
  int n = blockIdx.x*16 + wave*4 + g;
  int valid = (n < nN);
  int nc = valid ? n : (nN-1);

  int ro   = rowptr[nc];
  int degT = valid ? (rowptr[nc+1] - ro) : 0;   // includes self-loop slot

  float a0[8], a1[8], a2[8];
  #pragma unroll
  for (int c=0;c<8;c++){ a0[c]=0.f; a1[c]=0.f; a2[c]=0.f; }
  float den0=0.f, den1=0.f, den2=0.f;

  const unsigned short* hb = h_bf + 8*lin;
  const float4* vrow = val + ro;

  int j = 0;
  for (; j+1 < degT; j += 2){
    float4 vA = vrow[j];
    float4 vB = vrow[j+1];
    int sA = __float_as_int(vA.w);
    int sB = __float_as_int(vB.w);
    ushort8 ha = *(const ushort8*)(hb + (size_t)sA*128);
    ushort8 hc = *(const ushort8*)(hb + (size_t)sB*128);
    den0 += vA.x + vB.x; den1 += vA.y + vB.y; den2 += vA.z + vB.z;
    #pragma unroll
    for (int c=0;c<8;c++){
      float fa = bf2f(ha[c]), fb = bf2f(hc[c]);
      a0[c] += vA.x*fa + vB.x*fb;
      a1[c] += vA.y*fa + vB.y*fb;
      a2[c] += vA.z*fa + vB.z*fb;
    }
  }
  if (j < degT){
    float4 vA = vrow[j];
    int sA = __float_as_int(vA.w);
    ushort8 ha = *(const ushort8*)(hb + (size_t)sA*128);
    den0 += vA.x; den1 += vA.y; den2 += vA.z;
    #pragma unroll
    for (int c=0;c<8;c++){
      float fa = bf2f(ha[c]);
      a0[c] += vA.x*fa; a1[c] += vA.y*fa; a2[c] += vA.z*fa;
    }
  }

  if (valid){
    float w0 = 1.f/(den0+1e-16f);
    float w1 = 1.f/(den1+1e-16f);
    float w2 = 1.f/(den2+1e-16f);
    unsigned short o0[8], o1[8], o2[8];
    #pragma unroll
    for (int c=0;c<8;c++){
      o0[c] = f2bf(a0[c]*w0);
      o1[c] = f2bf(a1[c]*w1);
      o2[c] = f2bf(a2[c]*w2);
    }
    size_t bi = (size_t)n*384 + 8*lin;
    *(int4*)(hagg + bi      ) = *(int4*)o0;
    *(int4*)(hagg + bi + 128) = *(int4*)o1;
    *(int4*)(hagg + bi + 256) = *(int4*)o2;
  }
}

// ---- gemm2: LDS-staged B, double-buffered, software-pipelined ----
__global__ __launch_bounds__(256)
void gemm2_kernel(const unsigned short* __restrict__ hagg,
                  const unsigned short* __restrict__ Bt2,
                  const unsigned short* __restrict__ h_bf,
                  const float* __restrict__ gat_bias,
                  const float* __restrict__ out_w, const float* __restrict__ out_b,
                  float* __restrict__ out, int nN)
{
  __shared__ __align__(16) unsigned short Bs[2][128*PADK];
  int tid  = threadIdx.x;
  int wave = tid >> 6, lane = tid & 63;
  int cl = lane & 15, kg = lane >> 4;
  int r0 = blockIdx.x*64 + wave*16;
  int rowA = min(r0 + cl, nN-1);
  const unsigned short* aBase = hagg + (size_t)rowA*384 + kg*8;

  int scol = tid >> 1, shalf = tid & 1;
  int dstI = scol*(PADK/8) + shalf*2;

  {
    const int4* src = (const int4*)Bt2;
    int4 t0 = src[2*tid], t1 = src[2*tid+1];
    ((int4*)Bs[0])[dstI]   = t0;
    ((int4*)Bs[0])[dstI+1] = t1;
  }
  f32x4 acc[8];
  #pragma unroll
  for (int f=0;f<8;f++) acc[f] = (f32x4){0.f,0.f,0.f,0.f};
  bf16x8 aCur = *(const bf16x8*)(aBase);
  __syncthreads();

  #pragma unroll
  for (int ks=0; ks<12; ks++){
    int4 t0, t1; bf16x8 aNext;
    if (ks < 11){
      const int4* src = (const int4*)(Bt2 + (size_t)(ks+1)*4096);
      t0 = src[2*tid]; t1 = src[2*tid+1];
      aNext = *(const bf16x8*)(aBase + (ks+1)*32);
    }
    const unsigned short* bs = Bs[ks & 1];
    #pragma unroll
    for (int f=0;f<8;f++){
      bf16x8 b = *(const bf16x8*)(bs + (f*16 + cl)*PADK + kg*8);
      acc[f] = __builtin_amdgcn_mfma_f32_16x16x32_bf16(aCur, b, acc[f], 0, 0, 0);
    }
    if (ks < 11){
      int4* dst = (int4*)Bs[(ks+1) & 1];
      dst[dstI]   = t0;
      dst[dstI+1] = t1;
      aCur = aNext;
    }
    __syncthreads();
  }

  float p[4][4];
  #pragma unroll
  for (int r=0;r<4;r++)
    #pragma unroll
    for (int j=0;j<4;j++) p[r][j]=0.f;

  #pragma unroll
  for (int f=0;f<8;f++){
    int col = f*16 + cl;
    float bias = gat_bias[col];
    float w0=out_w[col*4+0], w1=out_w[col*4+1], w2=out_w[col*4+2], w3=out_w[col*4+3];
    #pragma unroll
    for (int r=0;r<4;r++){
      int row = r0 + kg*4 + r;
      float hres = (row < nN) ? bf2f(h_bf[(size_t)row*128 + col]) : 0.f;
      float xn = acc[f][r] + bias + hres;
      p[r][0] += xn*w0; p[r][1] += xn*w1; p[r][2] += xn*w2; p[r][3] += xn*w3;
    }
  }
  #pragma unroll
  for (int off=1; off<16; off<<=1){
    #pragma unroll
    for (int r=0;r<4;r++)
      #pragma unroll
      for (int j=0;j<4;j++) p[r][j] += __shfl_xor(p[r][j], off);
  }
  if (cl == 0){
    #pragma unroll
    for (int r=0;r<4;r++){
      int row = r0 + kg*4 + r;
      if (row < nN){
        float4 o = {p[r][0]+out_b[0], p[r][1]+out_b[1], p[r][2]+out_b[2], p[r][3]+out_b[3]};
        *(float4*)(out + (size_t)row*4) = o;
      }
    }
  }
}

extern "C" void kernel_launch(void* const* d_in, const int* in_sizes, int n_in,
                              void* d_out, int out_size, void* d_ws, size_t ws_size,
                              hipStream_t stream) {
  const float* x       = (const float*)d_in[0];
  const float* emb_w   = (const float*)d_in[1];
  const float* emb_b   = (const float*)d_in[2];
  const float* gat_w   = (const float*)d_in[3];
  const float* att_src = (const float*)d_in[4];
  const float* att_dst = (const float*)d_in[5];
  const float* gat_bias= (const float*)d_in[6];
  const float* out_w   = (const float*)d_in[7];
  const float* out_b   = (const float*)d_in[8];
  const int*   ei      = (const int*)d_in[9];
  float* out = (float*)d_out;

  int nN = in_sizes[0]/9;
  int nE = in_sizes[9]/2;
  int nB = (nN + SBS - 1) / SBS;     // 196
  int ebN = (nE + 255)/256;

  char* p = (char*)d_ws;
  auto alloc = [&](size_t bytes)->char*{
    char* r = p; p += (bytes + 255) & ~(size_t)255; return r;
  };
  unsigned short* h_bf   = (unsigned short*)alloc((size_t)nN*128*2);
  float*          a_s    = (float*)         alloc((size_t)nN*3*4);
  float*          a_d    = (float*)         alloc((size_t)nN*3*4);
  unsigned short* Bt2    = (unsigned short*)alloc((size_t)12*128*32*2);
  int*            deg    = (int*)           alloc((size_t)nN*4);
  int*            rowptr = (int*)           alloc(((size_t)nN+1)*4);
  int*            cursor = (int*)           alloc((size_t)nN*4);
  int*            bsum   = (int*)           alloc((size_t)nB*4);
  int*            boff   = (int*)           alloc((size_t)nB*4);
  float4*         val    = (float4*)        alloc(((size_t)nE+nN)*16);
  unsigned short* hagg   = (unsigned short*)alloc((size_t)nN*384*2);

  embed_kernel<<<nB, 256, 0, stream>>>(
      x, emb_w, emb_b, gat_w, att_src, att_dst, h_bf, a_s, a_d, deg, nN);

  deg_kernel<<<ebN + 192, 256, 0, stream>>>(ei, deg, gat_w, Bt2, nE, ebN);

  blocksum_kernel<<<nB, SBS, 0, stream>>>(deg, bsum, nN);
  scansum_kernel<<<1, 256, 0, stream>>>(bsum, boff, nB);
  blockscan_kernel<<<nB, SBS, 0, stream>>>(deg, boff, rowptr, cursor, nN);

  scatter_kernel<<<ebN + nB, 256, 0, stream>>>(
      ei, cursor, a_s, a_d, rowptr, val, nE, ebN, nN);

  gather_kernel<<<(nN+15)/16, 256, 0, stream>>>(
      rowptr, val, h_bf, hagg, nN);

  gemm2_kernel<<<(nN+63)/64, 256, 0, stream>>>(
      hagg, Bt2, h_bf, gat_bias, out_w, out_b, out, nN);
}